// Round 6
// baseline (236.632 us; speedup 1.0000x reference)
//
#include <hip/hip_runtime.h>
#include <hip/hip_bf16.h>

#define DIMF 512
#define NHEAD 8
#define DHEAD 64
#define BATCH 2
#define SEQN 2048
#define SEQM 2048
#define PPS 72    // P LDS row stride (bf16 elems)

typedef unsigned short u16;
typedef __attribute__((ext_vector_type(8))) short bf16x8;
typedef __attribute__((ext_vector_type(4))) float f32x4;

static __device__ __forceinline__ u16 f2bf(float f) {
    unsigned u = __float_as_uint(f);
    u += 0x7FFF + ((u >> 16) & 1);      // RNE
    return (u16)(u >> 16);
}
static __device__ __forceinline__ u16 f2bf_fast(float f) {
    return (u16)((__float_as_uint(f) + 0x8000u) >> 16);   // round-nearest (ties up)
}

static __device__ __forceinline__
void load16(const u16* g, u16* l) {
    __builtin_amdgcn_global_load_lds(
        (const __attribute__((address_space(1))) void*)g,
        (__attribute__((address_space(3))) void*)l,
        16, 0, 0);
}

// ---------------------------------------------------------------------------
// fp32 -> bf16 convert (+ mask int -> bf16 {0,1})
// ---------------------------------------------------------------------------
__global__ __launch_bounds__(256)
void cvt_bf16(const float* __restrict__ x, const float* __restrict__ src,
              const float* __restrict__ wq, const float* __restrict__ wk,
              const float* __restrict__ wv, const float* __restrict__ wm,
              const int* __restrict__ mask,
              u16* __restrict__ xb, u16* __restrict__ srcb,
              u16* __restrict__ wqb, u16* __restrict__ wkb,
              u16* __restrict__ wvb, u16* __restrict__ wmb,
              u16* __restrict__ maskbf)
{
    int i = (blockIdx.x * 256 + threadIdx.x) * 4;
    if (blockIdx.y == 6) {
        if (i >= BATCH * SEQM) return;
        int4 m4 = *(const int4*)&mask[i];
        *(ushort4*)&maskbf[i] = make_ushort4(m4.x ? 0x3F80 : 0, m4.y ? 0x3F80 : 0,
                                             m4.z ? 0x3F80 : 0, m4.w ? 0x3F80 : 0);
        return;
    }
    const float* in; u16* out; int n;
    switch (blockIdx.y) {
        case 0: in = x;   out = xb;   n = BATCH * SEQN * DIMF; break;
        case 1: in = src; out = srcb; n = BATCH * SEQM * DIMF; break;
        case 2: in = wq;  out = wqb;  n = DIMF * DIMF; break;
        case 3: in = wk;  out = wkb;  n = DIMF * DIMF; break;
        case 4: in = wv;  out = wvb;  n = DIMF * DIMF; break;
        default:in = wm;  out = wmb;  n = DIMF * DIMF; break;
    }
    if (i >= n) return;
    float4 v = *(const float4*)&in[i];
    *(ushort4*)&out[i] = make_ushort4(f2bf(v.x), f2bf(v.y), f2bf(v.z), f2bf(v.w));
}

// ---------------------------------------------------------------------------
// bf16 MFMA GEMM: Out = X(4096x512) @ W^T(512x512) + bias. 64x128 tile,
// 4 waves (2x2), wave 32x64 = 2x4 frags. global_load_lds width-16 staging.
// mode 0: q -> bf16 [B][H][n][d], (val+bias)*0.125
// mode 1: k -> bf16 [B][H][m][d]
// mode 2: v -> bf16 [B][H][m][d], masked rows zeroed (coalesced; transpose later)
// mode 3: fp32 row-major [4096][512]
// ---------------------------------------------------------------------------
__device__ __forceinline__
void gemm_mfma(const u16* __restrict__ X, const u16* __restrict__ W,
               const float* __restrict__ bias, const int* __restrict__ msk,
               void* __restrict__ Out, int mode)
{
    __shared__ u16 As[64 * 32];    // 4 KB
    __shared__ u16 Bs[128 * 32];   // 8 KB

    const int tid  = threadIdx.x;
    const int wave = tid >> 6;
    const int lane = tid & 63;
    const int l15  = lane & 15;
    const int quad = lane >> 4;
    const int wm = wave & 1, wn = wave >> 1;
    const int r0 = blockIdx.x * 64, c0 = blockIdx.y * 128;

    const u16* Ab = X + (size_t)r0 * DIMF;
    const u16* Bb = W + (size_t)c0 * DIMF;

    f32x4 acc[2][4] = {};
    const int arow = tid >> 2, akc = (tid & 3) << 3;

    for (int k0 = 0; k0 < DIMF; k0 += 32) {
        __syncthreads();
        load16(Ab + arow * DIMF + k0 + akc, (u16*)((char*)As + wave * 1024));
        #pragma unroll
        for (int i = 0; i < 2; ++i) {
            int chunk = i * 256 + tid;
            int row = chunk >> 2, kc = (chunk & 3) << 3;
            load16(Bb + row * DIMF + k0 + kc,
                   (u16*)((char*)Bs + i * 4096 + wave * 1024));
        }
        __syncthreads();

        bf16x8 af[2], bf[4];
        #pragma unroll
        for (int mi = 0; mi < 2; ++mi)
            af[mi] = *(const bf16x8*)&As[(wm * 32 + mi * 16 + l15) * 32 + quad * 8];
        #pragma unroll
        for (int ni = 0; ni < 4; ++ni)
            bf[ni] = *(const bf16x8*)&Bs[(wn * 64 + ni * 16 + l15) * 32 + quad * 8];
        #pragma unroll
        for (int mi = 0; mi < 2; ++mi)
            #pragma unroll
            for (int ni = 0; ni < 4; ++ni)
                acc[mi][ni] = __builtin_amdgcn_mfma_f32_16x16x32_bf16(
                    af[mi], bf[ni], acc[mi][ni], 0, 0, 0);
    }

    float bb[4];
    #pragma unroll
    for (int ni = 0; ni < 4; ++ni)
        bb[ni] = bias[c0 + wn * 64 + ni * 16 + l15];

    #pragma unroll
    for (int mi = 0; mi < 2; ++mi) {
        const int Rbase = r0 + wm * 32 + mi * 16 + quad * 4;   // +r, r=0..3
        const int b = Rbase >> 11;
        const int nb = Rbase & (SEQN - 1);
        float mm[4] = {1.f, 1.f, 1.f, 1.f};
        if (mode == 2) {
            int4 m4 = *(const int4*)&msk[b * SEQM + nb];
            mm[0] = m4.x ? 1.f : 0.f; mm[1] = m4.y ? 1.f : 0.f;
            mm[2] = m4.z ? 1.f : 0.f; mm[3] = m4.w ? 1.f : 0.f;
        }
        #pragma unroll
        for (int ni = 0; ni < 4; ++ni) {
            const int C = c0 + wn * 64 + ni * 16 + l15;
            const int h = C >> 6, d = C & 63;
            if (mode == 0) {
                u16* ow = (u16*)Out;
                #pragma unroll
                for (int r = 0; r < 4; ++r)
                    ow[(((size_t)(b * NHEAD + h) * SEQN) + nb + r) * DHEAD + d] =
                        f2bf((acc[mi][ni][r] + bb[ni]) * 0.125f);
            } else if (mode == 1) {
                u16* ow = (u16*)Out;
                #pragma unroll
                for (int r = 0; r < 4; ++r)
                    ow[(((size_t)(b * NHEAD + h) * SEQN) + nb + r) * DHEAD + d] =
                        f2bf(acc[mi][ni][r] + bb[ni]);
            } else if (mode == 2) {
                u16* ow = (u16*)Out;
                #pragma unroll
                for (int r = 0; r < 4; ++r)
                    ow[(((size_t)(b * NHEAD + h) * SEQN) + nb + r) * DHEAD + d] =
                        f2bf((acc[mi][ni][r] + bb[ni]) * mm[r]);
            } else {
                float* ow = (float*)Out;
                #pragma unroll
                for (int r = 0; r < 4; ++r)
                    ow[(size_t)(Rbase + r) * DIMF + C] = acc[mi][ni][r] + bb[ni];
            }
        }
    }
}

__global__ __launch_bounds__(256, 4)
void qkv_proj(const u16* __restrict__ xb, const u16* __restrict__ srcb,
              const u16* __restrict__ wqb, const float* __restrict__ bq,
              const u16* __restrict__ wkb, const float* __restrict__ bk,
              const u16* __restrict__ wvb, const float* __restrict__ bv,
              const int* __restrict__ mask,
              u16* __restrict__ qw, u16* __restrict__ kw, u16* __restrict__ vw)
{
    const int z = blockIdx.z;
    const u16* X = (z == 0) ? xb  : srcb;
    const u16* W = (z == 0) ? wqb : (z == 1) ? wkb : wvb;
    const float* B = (z == 0) ? bq : (z == 1) ? bk : bv;
    void* O = (z == 0) ? (void*)qw : (z == 1) ? (void*)kw : (void*)vw;
    gemm_mfma(X, W, B, mask, O, z);
}

__global__ __launch_bounds__(256, 4)
void out_proj(const u16* __restrict__ aggb, const u16* __restrict__ wmb,
              const float* __restrict__ bm, float* __restrict__ out)
{
    gemm_mfma(aggb, wmb, bm, nullptr, (void*)out, 3);
}

// ---------------------------------------------------------------------------
// V [bh][m][d] -> V^T [bh][d][m], LDS-tiled (both sides coalesced)
// ---------------------------------------------------------------------------
__global__ __launch_bounds__(256)
void vtr(const u16* __restrict__ v, u16* __restrict__ vt)
{
    __shared__ u16 T[64 * 72];
    const int tid = threadIdx.x;
    const int m0 = blockIdx.x * 64, bh = blockIdx.y;
    const u16* src = v + ((size_t)bh * SEQM + m0) * DHEAD;
    const int r = tid >> 3, c = (tid & 7) << 3;
    *(bf16x8*)&T[r * 72 + c]        = *(const bf16x8*)&src[r * DHEAD + c];
    *(bf16x8*)&T[(r + 32) * 72 + c] = *(const bf16x8*)&src[(r + 32) * DHEAD + c];
    __syncthreads();
    const int d = tid >> 2, mc = (tid & 3) << 4;
    u16 tmp[16];
    #pragma unroll
    for (int j = 0; j < 16; ++j) tmp[j] = T[(mc + j) * 72 + d];
    u16* dst = vt + ((size_t)bh * DHEAD + d) * SEQM + m0 + mc;
    *(bf16x8*)&dst[0] = *(bf16x8*)&tmp[0];
    *(bf16x8*)&dst[8] = *(bf16x8*)&tmp[8];
}

// ---------------------------------------------------------------------------
// Wave-independent MFMA flash attention. Wave = (b, h, 16 q-rows); NO
// __syncthreads in the loop. K / V^T fragments loaded direct global->VGPR
// (L2-resident per head). Fixed-base softmax (|s|<=8 by Cauchy-Schwarz,
// exp never overflows). Mask is OUT of the loop: V rows pre-zeroed, l
// accumulated by an extra MFMA vs a bf16 mask-row B-fragment (broadcast
// over n) -> lacc[r] lands exactly on O's row layout, no shuffles.
// LDS: wave-private P^T round-trip only (9 KB/block).
// ---------------------------------------------------------------------------
__global__ __launch_bounds__(256, 2)
void flash_attn_mfma(const u16* __restrict__ q, const u16* __restrict__ k,
                     const u16* __restrict__ vt, const u16* __restrict__ maskbf,
                     u16* __restrict__ agg)
{
    __shared__ u16 Ps[4][16 * PPS];     // per-wave [q(16)][m(64)]

    const int tid  = threadIdx.x;
    const int wave = tid >> 6;
    const int lane = tid & 63;
    const int l15  = lane & 15;
    const int quad = lane >> 4;
    const int w  = blockIdx.x * 4 + wave;     // 0..2047
    const int qt = w & 127;
    const int h  = (w >> 7) & 7;
    const int b  = w >> 10;
    const int n0 = qt * 16;
    const size_t hoff = (size_t)(b * NHEAD + h) * (size_t)SEQM * DHEAD;
    const u16* kb = k  + hoff;
    const u16* vb = vt + hoff;
    const u16* mb = maskbf + b * SEQM;
    u16* Pw = &Ps[wave][0];

    // Q B-fragments (prescaled 1/8): col q = n0+l15, k = 32c+quad*8+j
    bf16x8 qf[2];
    {
        const u16* qp = q + hoff + (size_t)(n0 + l15) * DHEAD + quad * 8;
        qf[0] = *(const bf16x8*)qp;
        qf[1] = *(const bf16x8*)(qp + 32);
    }

    f32x4 O[4] = {};     // O[sd]: row q = quad*4+r, col d = 16*sd+l15
    f32x4 lacc = {};     // l via mask-MFMA: lacc[r] = l[q=quad*4+r]

    for (int m0 = 0; m0 < SEQM; m0 += 64) {
        // S^T = K.Q^T : rows m = 16*sub+quad*4+r, col q = l15
        f32x4 st[4] = {};
        #pragma unroll
        for (int sub = 0; sub < 4; ++sub) {
            #pragma unroll
            for (int c = 0; c < 2; ++c) {
                bf16x8 af = *(const bf16x8*)
                    &kb[(size_t)(m0 + 16 * sub + l15) * DHEAD + 32 * c + quad * 8];
                st[sub] = __builtin_amdgcn_mfma_f32_16x16x32_bf16(af, qf[c], st[sub], 0, 0, 0);
            }
        }
        // p = exp(s) unmasked (masked m: V row zero + mask frag zero)
        #pragma unroll
        for (int sub = 0; sub < 4; ++sub) {
            ushort4 w4 = make_ushort4(f2bf_fast(__expf(st[sub][0])),
                                      f2bf_fast(__expf(st[sub][1])),
                                      f2bf_fast(__expf(st[sub][2])),
                                      f2bf_fast(__expf(st[sub][3])));
            *(ushort4*)&Pw[l15 * PPS + 16 * sub + 4 * quad] = w4;   // m = 16sub+4quad+r
        }
        // PV + l over the two 32-m halves (wave-private LDS, lgkmcnt only)
        #pragma unroll
        for (int kh = 0; kh < 2; ++kh) {
            bf16x8 pf = *(const bf16x8*)&Pw[l15 * PPS + kh * 32 + quad * 8];
            bf16x8 mf = *(const bf16x8*)&mb[m0 + kh * 32 + quad * 8];   // bcast over l15
            lacc = __builtin_amdgcn_mfma_f32_16x16x32_bf16(pf, mf, lacc, 0, 0, 0);
            #pragma unroll
            for (int sd = 0; sd < 4; ++sd) {
                bf16x8 vf = *(const bf16x8*)
                    &vb[(size_t)(16 * sd + l15) * SEQM + m0 + kh * 32 + quad * 8];
                O[sd] = __builtin_amdgcn_mfma_f32_16x16x32_bf16(pf, vf, O[sd], 0, 0, 0);
            }
        }
    }

    // epilogue: no shuffles; lacc[r] is l for q-row quad*4+r
    #pragma unroll
    for (int r = 0; r < 4; ++r) {
        const float inv = 1.f / lacc[r];
        const int n = n0 + quad * 4 + r;
        u16* ag = agg + ((size_t)b * SEQN + n) * DIMF + h * DHEAD + l15;
        #pragma unroll
        for (int sd = 0; sd < 4; ++sd)
            ag[16 * sd] = f2bf(O[sd][r] * inv);
    }
}

extern "C" void kernel_launch(void* const* d_in, const int* in_sizes, int n_in,
                              void* d_out, int out_size, void* d_ws, size_t ws_size,
                              hipStream_t stream)
{
    (void)in_sizes; (void)n_in; (void)out_size; (void)ws_size;
    const float* x      = (const float*)d_in[0];
    const float* source = (const float*)d_in[1];
    const int*   mask   = (const int*)  d_in[2];
    const float* Wq = (const float*)d_in[3]; const float* bq = (const float*)d_in[4];
    const float* Wk = (const float*)d_in[5]; const float* bk = (const float*)d_in[6];
    const float* Wv = (const float*)d_in[7]; const float* bv = (const float*)d_in[8];
    const float* Wm = (const float*)d_in[9]; const float* bm = (const float*)d_in[10];
    float* out = (float*)d_out;

    const size_t SZ = (size_t)BATCH * SEQN * DIMF;   // 2,097,152 elems
    const size_t WZ = (size_t)DIMF * DIMF;
    u16* qw   = (u16*)d_ws;          // bf16 [B][H][n][d] (x0.125, +bq)
    u16* kw   = qw  + SZ;            // bf16 [B][H][m][d]
    u16* vw   = kw  + SZ;            // bf16 [B][H][m][d] masked  -- aliased:
    u16* aggb = vw;                  //   agg (flash output; vw dead after vtr)
    u16* xb   = vw  + SZ;            // bf16 x (dead after qkv)   -- aliased:
    u16* vtw  = xb;                  //   bf16 V^T [B][H][d][m] (written by vtr)
    u16* srcb = xb  + SZ;
    u16* wqb  = srcb + SZ;
    u16* wkb  = wqb + WZ;
    u16* wvb  = wkb + WZ;
    u16* wmb  = wvb + WZ;
    u16* maskbf = wmb + WZ;          // bf16 [B][M] {0,1}; total ~22.1 MB

    dim3 gcvt((SZ / 4 + 255) / 256, 7);
    cvt_bf16<<<gcvt, 256, 0, stream>>>(x, source, Wq, Wk, Wv, Wm, mask,
                                       xb, srcb, wqb, wkb, wvb, wmb, maskbf);

    dim3 gproj(4096 / 64, 512 / 128, 3);    // 768 blocks
    qkv_proj<<<gproj, 256, 0, stream>>>(xb, srcb, wqb, bq, wkb, bk, wvb, bv,
                                        mask, qw, kw, vw);

    dim3 gvtr(SEQM / 64, BATCH * NHEAD);    // 512 tiny blocks
    vtr<<<gvtr, 256, 0, stream>>>(vw, vtw);

    dim3 gattn(2048 / 4);                   // 512 blocks x 4 independent waves
    flash_attn_mfma<<<gattn, 256, 0, stream>>>(qw, kw, vtw, maskbf, aggb);

    dim3 gout(4096 / 64, 512 / 128);        // 256 blocks
    out_proj<<<gout, 256, 0, stream>>>(aggb, wmb, bm, out);
}

// Round 7
// 153.017 us; speedup vs baseline: 1.5464x; 1.5464x over previous
//
#include <hip/hip_runtime.h>
#include <hip/hip_bf16.h>

#define DIMF 512
#define NHEAD 8
#define DHEAD 64
#define BATCH 2
#define SEQN 2048
#define SEQM 2048
#define FPS 40        // P LDS row stride (u16): 32 data + 8 pad -> 2-way banks
#define QSCALE 0.18033688011112042f   // 0.125 * log2(e)

typedef unsigned short u16;
typedef __attribute__((ext_vector_type(8))) short bf16x8;
typedef __attribute__((ext_vector_type(4))) float f32x4;

static __device__ __forceinline__ u16 f2bf(float f) {
    unsigned u = __float_as_uint(f);
    u += 0x7FFF + ((u >> 16) & 1);      // RNE
    return (u16)(u >> 16);
}
static __device__ __forceinline__ u16 f2bf_fast(float f) {
    return (u16)((__float_as_uint(f) + 0x8000u) >> 16);
}

static __device__ __forceinline__
void load16(const u16* g, u16* l) {
    __builtin_amdgcn_global_load_lds(
        (const __attribute__((address_space(1))) void*)g,
        (__attribute__((address_space(3))) void*)l,
        16, 0, 0);
}

// ---------------------------------------------------------------------------
// weights fp32 -> bf16 (+ mask int -> bf16 {0,1})
// ---------------------------------------------------------------------------
__global__ __launch_bounds__(256)
void cvt_w(const float* __restrict__ wq, const float* __restrict__ wk,
           const float* __restrict__ wv, const float* __restrict__ wm,
           const int* __restrict__ mask,
           u16* __restrict__ wqb, u16* __restrict__ wkb,
           u16* __restrict__ wvb, u16* __restrict__ wmb,
           u16* __restrict__ maskbf)
{
    int i = (blockIdx.x * 256 + threadIdx.x) * 4;
    if (blockIdx.y == 4) {
        if (i < BATCH * SEQM) {
            int4 m4 = *(const int4*)&mask[i];
            *(ushort4*)&maskbf[i] = make_ushort4(m4.x ? 0x3F80 : 0, m4.y ? 0x3F80 : 0,
                                                 m4.z ? 0x3F80 : 0, m4.w ? 0x3F80 : 0);
        }
        return;
    }
    const float* in = (blockIdx.y == 0) ? wq : (blockIdx.y == 1) ? wk
                    : (blockIdx.y == 2) ? wv : wm;
    u16* out = (blockIdx.y == 0) ? wqb : (blockIdx.y == 1) ? wkb
             : (blockIdx.y == 2) ? wvb : wmb;
    if (i >= DIMF * DIMF) return;
    float4 v = *(const float4*)&in[i];
    *(ushort4*)&out[i] = make_ushort4(f2bf(v.x), f2bf(v.y), f2bf(v.z), f2bf(v.w));
}

// ---------------------------------------------------------------------------
// bf16 MFMA GEMM, 64x128 tile, 4 waves (2x2), wave 32x64 = 2x4 frags.
// A staged from fp32 (Xf, fused cvt) or bf16 (Xb). Padded LDS stride 40 u16
// -> frag reads 2-way only (the old unpadded layout was 8-way = 2.94x).
// Global loads issued before the staging barrier (overlap w/ prior MFMAs).
// mode 0: q -> bf16 [B][H][n][d], (val+bias)*QSCALE (softmax+exp2 folded)
// mode 1: k -> bf16 [B][H][m][d]
// mode 2: v -> bf16 [B][H][m][d], masked rows zeroed
// mode 3: fp32 row-major [4096][512]
// ---------------------------------------------------------------------------
__device__ __forceinline__
void gemm_mfma(const float* __restrict__ Xf, const u16* __restrict__ Xb,
               const u16* __restrict__ W, const float* __restrict__ bias,
               const int* __restrict__ msk, void* __restrict__ Out, int mode)
{
    __shared__ u16 As[64 * FPS];    // 5 KB
    __shared__ u16 Bs[128 * FPS];   // 10 KB

    const int tid  = threadIdx.x;
    const int wave = tid >> 6;
    const int lane = tid & 63;
    const int l15  = lane & 15;
    const int quad = lane >> 4;
    const int wm = wave & 1, wn = wave >> 1;
    const int r0 = blockIdx.x * 64, c0 = blockIdx.y * 128;

    f32x4 acc[2][4] = {};

    const int br = tid >> 2, boct = tid & 3;        // B: rows br, br+64
    const int ar = tid >> 3, aseg = tid & 7;        // A fp32: rows ar, ar+32

    for (int k0 = 0; k0 < DIMF; k0 += 32) {
        // global loads first (overlap with previous iteration's compute)
        bf16x8 bv0 = *(const bf16x8*)&W[(size_t)(c0 + br) * DIMF + k0 + boct * 8];
        bf16x8 bv1 = *(const bf16x8*)&W[(size_t)(c0 + br + 64) * DIMF + k0 + boct * 8];
        float4 a0, a1; bf16x8 av;
        if (Xf) {
            a0 = *(const float4*)&Xf[(size_t)(r0 + ar) * DIMF + k0 + aseg * 4];
            a1 = *(const float4*)&Xf[(size_t)(r0 + ar + 32) * DIMF + k0 + aseg * 4];
        } else {
            av = *(const bf16x8*)&Xb[(size_t)(r0 + br) * DIMF + k0 + boct * 8];
        }
        __syncthreads();   // prior tile's frag reads done
        if (Xf) {
            *(ushort4*)&As[ar * FPS + aseg * 4] =
                make_ushort4(f2bf(a0.x), f2bf(a0.y), f2bf(a0.z), f2bf(a0.w));
            *(ushort4*)&As[(ar + 32) * FPS + aseg * 4] =
                make_ushort4(f2bf(a1.x), f2bf(a1.y), f2bf(a1.z), f2bf(a1.w));
        } else {
            *(bf16x8*)&As[br * FPS + boct * 8] = av;
        }
        *(bf16x8*)&Bs[br * FPS + boct * 8] = bv0;
        *(bf16x8*)&Bs[(br + 64) * FPS + boct * 8] = bv1;
        __syncthreads();

        bf16x8 af[2], bf[4];
        #pragma unroll
        for (int mi = 0; mi < 2; ++mi)
            af[mi] = *(const bf16x8*)&As[(wm * 32 + mi * 16 + l15) * FPS + quad * 8];
        #pragma unroll
        for (int ni = 0; ni < 4; ++ni)
            bf[ni] = *(const bf16x8*)&Bs[(wn * 64 + ni * 16 + l15) * FPS + quad * 8];
        #pragma unroll
        for (int mi = 0; mi < 2; ++mi)
            #pragma unroll
            for (int ni = 0; ni < 4; ++ni)
                acc[mi][ni] = __builtin_amdgcn_mfma_f32_16x16x32_bf16(
                    af[mi], bf[ni], acc[mi][ni], 0, 0, 0);
    }

    float bb[4];
    #pragma unroll
    for (int ni = 0; ni < 4; ++ni)
        bb[ni] = bias[c0 + wn * 64 + ni * 16 + l15];

    #pragma unroll
    for (int mi = 0; mi < 2; ++mi) {
        const int Rbase = r0 + wm * 32 + mi * 16 + quad * 4;   // +r, r=0..3
        const int b = Rbase >> 11;
        const int nb = Rbase & (SEQN - 1);
        float mm[4] = {1.f, 1.f, 1.f, 1.f};
        if (mode == 2) {
            int4 m4 = *(const int4*)&msk[b * SEQM + nb];
            mm[0] = m4.x ? 1.f : 0.f; mm[1] = m4.y ? 1.f : 0.f;
            mm[2] = m4.z ? 1.f : 0.f; mm[3] = m4.w ? 1.f : 0.f;
        }
        #pragma unroll
        for (int ni = 0; ni < 4; ++ni) {
            const int C = c0 + wn * 64 + ni * 16 + l15;
            const int h = C >> 6, d = C & 63;
            if (mode == 0) {
                u16* ow = (u16*)Out;
                #pragma unroll
                for (int r = 0; r < 4; ++r)
                    ow[(((size_t)(b * NHEAD + h) * SEQN) + nb + r) * DHEAD + d] =
                        f2bf((acc[mi][ni][r] + bb[ni]) * QSCALE);
            } else if (mode == 1) {
                u16* ow = (u16*)Out;
                #pragma unroll
                for (int r = 0; r < 4; ++r)
                    ow[(((size_t)(b * NHEAD + h) * SEQN) + nb + r) * DHEAD + d] =
                        f2bf(acc[mi][ni][r] + bb[ni]);
            } else if (mode == 2) {
                u16* ow = (u16*)Out;
                #pragma unroll
                for (int r = 0; r < 4; ++r)
                    ow[(((size_t)(b * NHEAD + h) * SEQN) + nb + r) * DHEAD + d] =
                        f2bf((acc[mi][ni][r] + bb[ni]) * mm[r]);
            } else {
                float* ow = (float*)Out;
                #pragma unroll
                for (int r = 0; r < 4; ++r)
                    ow[(size_t)(Rbase + r) * DIMF + C] = acc[mi][ni][r] + bb[ni];
            }
        }
    }
}

__global__ __launch_bounds__(256, 4)
void qkv_proj(const float* __restrict__ x, const float* __restrict__ src,
              const u16* __restrict__ wqb, const float* __restrict__ bq,
              const u16* __restrict__ wkb, const float* __restrict__ bk,
              const u16* __restrict__ wvb, const float* __restrict__ bv,
              const int* __restrict__ mask,
              u16* __restrict__ qw, u16* __restrict__ kw, u16* __restrict__ vw)
{
    const int z = blockIdx.z;
    const float* X = (z == 0) ? x : src;
    const u16* W = (z == 0) ? wqb : (z == 1) ? wkb : wvb;
    const float* B = (z == 0) ? bq : (z == 1) ? bk : bv;
    void* O = (z == 0) ? (void*)qw : (z == 1) ? (void*)kw : (void*)vw;
    gemm_mfma(X, nullptr, W, B, mask, O, z);
}

__global__ __launch_bounds__(256, 4)
void out_proj(const u16* __restrict__ aggb, const u16* __restrict__ wmb,
              const float* __restrict__ bm, float* __restrict__ out)
{
    gemm_mfma(nullptr, aggb, wmb, bm, nullptr, (void*)out, 3);
}

// ---------------------------------------------------------------------------
// V [bh][m][d] -> V^T [bh][d][m], LDS-tiled (both sides coalesced)
// ---------------------------------------------------------------------------
__global__ __launch_bounds__(256)
void vtr(const u16* __restrict__ v, u16* __restrict__ vt)
{
    __shared__ u16 T[64 * 72];
    const int tid = threadIdx.x;
    const int m0 = blockIdx.x * 64, bh = blockIdx.y;
    const u16* src = v + ((size_t)bh * SEQM + m0) * DHEAD;
    const int r = tid >> 3, c = (tid & 7) << 3;
    *(bf16x8*)&T[r * 72 + c]        = *(const bf16x8*)&src[r * DHEAD + c];
    *(bf16x8*)&T[(r + 32) * 72 + c] = *(const bf16x8*)&src[(r + 32) * DHEAD + c];
    __syncthreads();
    const int d = tid >> 2, mc = (tid & 3) << 4;
    u16 tmp[16];
    #pragma unroll
    for (int j = 0; j < 16; ++j) tmp[j] = T[(mc + j) * 72 + d];
    u16* dst = vt + ((size_t)bh * DHEAD + d) * SEQM + m0 + mc;
    *(bf16x8*)&dst[0] = *(bf16x8*)&tmp[0];
    *(bf16x8*)&dst[8] = *(bf16x8*)&tmp[8];
}

// ---------------------------------------------------------------------------
// MFMA flash attention v3.
// Block = (b, h, 32 q-rows); 4 waves = 2 q-groups x 2 m-halves (R5 shape,
// grid 1024 -> 4 blocks/CU). K/V^T tiles staged by async global_load_lds
// into XOR-SWIZZLED LDS: slot(row,oct) = row*8 + (oct^(row&7)) [16B units].
// The DMA's lane-contiguous write maps onto this by permuting each lane's
// global source octet (coalescing preserved); fragment reads are 2-way max.
// Lean loop (R6): p = exp2(s) (scale folded into q), no mask/no shuffles in
// loop; V rows pre-zeroed; l via mask-row MFMA -> lacc[r] lands on O rows.
// Epilogue: m-halves combined through LDS unioned over K/V tiles.
// ---------------------------------------------------------------------------
__global__ __launch_bounds__(256, 4)
void flash_attn_mfma(const u16* __restrict__ q, const u16* __restrict__ k,
                     const u16* __restrict__ vt, const u16* __restrict__ maskbf,
                     u16* __restrict__ agg)
{
    __shared__ __align__(16) u16 Ks[4096];    // 8 KB swizzled [m][oct]
    __shared__ __align__(16) u16 Vts[4096];   // 8 KB swizzled [d][oct_m]
    __shared__ u16 Ps[4][16 * FPS];           // 5 KB per-wave P^T
    float* Osum = (float*)Ks;                 // epilogue union: [2][16][64]
    float* Lsum = (float*)Vts;                // [2][16]

    const int tid  = threadIdx.x;
    const int wave = tid >> 6;
    const int lane = tid & 63;
    const int l15  = lane & 15;
    const int quad = lane >> 4;
    const int qg = wave >> 1, mh = wave & 1;
    const int qt = blockIdx.x, h = blockIdx.y, b = blockIdx.z;
    const int n0 = qt * 32;
    const size_t hoff = (size_t)(b * NHEAD + h) * (size_t)SEQM * DHEAD;
    const u16* kb = k  + hoff;
    const u16* vb = vt + hoff;
    const u16* mb = maskbf + b * SEQM;

    // DMA geometry: instr group g covers LDS slots [64g,64g+64); lane l ->
    // row = 8g + (l>>3), stored oct' = l&7  =>  source oct = (l&7)^((l>>3)&7)
    const int dr   = lane >> 3;
    const int doct = (lane & 7) ^ (dr & 7);
    const int g0 = wave, g1 = 4 + wave;
    const u16* kq0 = kb + (size_t)(g0 * 8 + dr) * DHEAD + doct * 8;
    const u16* kq1 = kb + (size_t)(g1 * 8 + dr) * DHEAD + doct * 8;
    const u16* vq0 = vb + (size_t)(g0 * 8 + dr) * SEQM + doct * 8;
    const u16* vq1 = vb + (size_t)(g1 * 8 + dr) * SEQM + doct * 8;
    u16* kl0 = Ks  + g0 * 512;  u16* kl1 = Ks  + g1 * 512;
    u16* vl0 = Vts + g0 * 512;  u16* vl1 = Vts + g1 * 512;

    // Q B-frags (prescaled by 0.125*log2e): col q = n0+qg*16+l15
    bf16x8 qf[2];
    {
        const u16* qp = q + hoff + (size_t)(n0 + qg * 16 + l15) * DHEAD + quad * 8;
        qf[0] = *(const bf16x8*)qp;
        qf[1] = *(const bf16x8*)(qp + 32);
    }

    f32x4 O[4] = {};     // row q = quad*4+r, col d = 16*sd+l15 (mh-half partial)
    f32x4 lacc = {};     // lacc[r] = partial l[q = quad*4+r]
    u16* Pw = &Ps[wave][0];
    const int xoct = l15 & 7;

    for (int m0 = 0; m0 < SEQM; m0 += 64) {
        __syncthreads();   // prior tile's LDS reads done
        load16(kq0 + (size_t)m0 * DHEAD, kl0);
        load16(kq1 + (size_t)m0 * DHEAD, kl1);
        load16(vq0 + m0, vl0);
        load16(vq1 + m0, vl1);
        __syncthreads();   // compiler drains vmcnt before barrier -> DMA done

        // S^T (this wave's 32-m half): rows m = 32mh+16sub+quad*4+r, col q=l15
        f32x4 st[2] = {};
        #pragma unroll
        for (int sub = 0; sub < 2; ++sub) {
            const int mrow = 32 * mh + 16 * sub + l15;
            #pragma unroll
            for (int c = 0; c < 2; ++c) {
                const int oct = (4 * c + quad) ^ xoct;
                bf16x8 af = *(const bf16x8*)&Ks[mrow * 64 + oct * 8];
                st[sub] = __builtin_amdgcn_mfma_f32_16x16x32_bf16(af, qf[c], st[sub], 0, 0, 0);
            }
        }

        // p = 2^s, pack, P^T -> wave-private LDS (no barrier; lgkm only)
        #pragma unroll
        for (int sub = 0; sub < 2; ++sub) {
            ushort4 w4 = make_ushort4(
                f2bf_fast(__builtin_amdgcn_exp2f(st[sub][0])),
                f2bf_fast(__builtin_amdgcn_exp2f(st[sub][1])),
                f2bf_fast(__builtin_amdgcn_exp2f(st[sub][2])),
                f2bf_fast(__builtin_amdgcn_exp2f(st[sub][3])));
            *(ushort4*)&Pw[l15 * FPS + 16 * sub + 4 * quad] = w4;
        }

        bf16x8 pf = *(const bf16x8*)&Pw[l15 * FPS + quad * 8];
        bf16x8 mf = *(const bf16x8*)&mb[m0 + 32 * mh + quad * 8];
        lacc = __builtin_amdgcn_mfma_f32_16x16x32_bf16(pf, mf, lacc, 0, 0, 0);
        #pragma unroll
        for (int sd = 0; sd < 4; ++sd) {
            const int d = 16 * sd + l15;
            const int oct = (4 * mh + quad) ^ xoct;
            bf16x8 vf = *(const bf16x8*)&Vts[d * 64 + oct * 8];
            O[sd] = __builtin_amdgcn_mfma_f32_16x16x32_bf16(pf, vf, O[sd], 0, 0, 0);
        }
    }

    // combine the two m-halves per q-group (LDS unioned over K/V tiles)
    __syncthreads();
    if (mh == 1) {
        #pragma unroll
        for (int sd = 0; sd < 4; ++sd)
            #pragma unroll
            for (int r = 0; r < 4; ++r)
                Osum[qg * 1024 + (quad * 4 + r) * 64 + 16 * sd + l15] = O[sd][r];
        if (l15 == 0) {
            #pragma unroll
            for (int r = 0; r < 4; ++r) Lsum[qg * 16 + quad * 4 + r] = lacc[r];
        }
    }
    __syncthreads();
    if (mh == 0) {
        #pragma unroll
        for (int r = 0; r < 4; ++r) {
            const float inv = 1.f / (lacc[r] + Lsum[qg * 16 + quad * 4 + r]);
            const int n = n0 + qg * 16 + quad * 4 + r;
            u16* ag = agg + ((size_t)b * SEQN + n) * DIMF + h * DHEAD + l15;
            #pragma unroll
            for (int sd = 0; sd < 4; ++sd)
                ag[16 * sd] = f2bf((O[sd][r] +
                    Osum[qg * 1024 + (quad * 4 + r) * 64 + 16 * sd + l15]) * inv);
        }
    }
}

extern "C" void kernel_launch(void* const* d_in, const int* in_sizes, int n_in,
                              void* d_out, int out_size, void* d_ws, size_t ws_size,
                              hipStream_t stream)
{
    (void)in_sizes; (void)n_in; (void)out_size; (void)ws_size;
    const float* x      = (const float*)d_in[0];
    const float* source = (const float*)d_in[1];
    const int*   mask   = (const int*)  d_in[2];
    const float* Wq = (const float*)d_in[3]; const float* bq = (const float*)d_in[4];
    const float* Wk = (const float*)d_in[5]; const float* bk = (const float*)d_in[6];
    const float* Wv = (const float*)d_in[7]; const float* bv = (const float*)d_in[8];
    const float* Wm = (const float*)d_in[9]; const float* bm = (const float*)d_in[10];
    float* out = (float*)d_out;

    const size_t SZ = (size_t)BATCH * SEQN * DIMF;   // 2,097,152 elems
    const size_t WZ = (size_t)DIMF * DIMF;
    u16* qw   = (u16*)d_ws;          // bf16 [B][H][n][d] (xQSCALE, +bq)
    u16* kw   = qw  + SZ;            // bf16 [B][H][m][d]
    u16* vw   = kw  + SZ;            // bf16 [B][H][m][d] masked  -- aliased:
    u16* aggb = vw;                  //   agg (flash out; vw dead after vtr)
    u16* vtw  = vw  + SZ;            // bf16 V^T [B][H][d][m]
    u16* wqb  = vtw + SZ;
    u16* wkb  = wqb + WZ;
    u16* wvb  = wkb + WZ;
    u16* wmb  = wvb + WZ;
    u16* maskbf = wmb + WZ;          // bf16 [B][M] {0,1}; ~19 MB total

    dim3 gcvt((WZ / 4 + 255) / 256, 5);     // 256 x 5 blocks
    cvt_w<<<gcvt, 256, 0, stream>>>(Wq, Wk, Wv, Wm, mask,
                                    wqb, wkb, wvb, wmb, maskbf);

    dim3 gproj(4096 / 64, 512 / 128, 3);    // 768 blocks
    qkv_proj<<<gproj, 256, 0, stream>>>(x, source, wqb, bq, wkb, bk, wvb, bv,
                                        mask, qw, kw, vw);

    dim3 gvtr(SEQM / 64, BATCH * NHEAD);    // 512 tiny blocks
    vtr<<<gvtr, 256, 0, stream>>>(vw, vtw);

    dim3 gattn(SEQN / 32, NHEAD, BATCH);    // 1024 blocks
    flash_attn_mfma<<<gattn, 256, 0, stream>>>(qw, kw, vtw, maskbf, aggb);

    dim3 gout(4096 / 64, 512 / 128);        // 256 blocks
    out_proj<<<gout, 256, 0, stream>>>(aggb, wmb, bm, out);
}